// Round 1
// baseline (129.771 us; speedup 1.0000x reference)
//
#include <hip/hip_runtime.h>
#include <math.h>

static constexpr int B_ = 32;
static constexpr int T_ = 512;
static constexpr int H_ = 768;
static constexpr int NL = 12;                 // layers 1..12 of 13
static constexpr int CHUNKS = 64;             // blocks per batch item
static constexpr int TOK_PER_BLK = T_ / CHUNKS;   // 8
static constexpr int THREADS = H_ / 4;        // 192 (3 waves)

// Order-preserving float -> uint encoding so unsigned atomicMax == float max.
__device__ __forceinline__ unsigned fenc(float f) {
  unsigned u = __float_as_uint(f);
  return (u & 0x80000000u) ? ~u : (u | 0x80000000u);
}
__device__ __forceinline__ float fdec(unsigned e) {
  return __uint_as_float((e & 0x80000000u) ? (e ^ 0x80000000u) : ~e);
}

__global__ void init_pooled(unsigned* __restrict__ p, int n) {
  int i = blockIdx.x * blockDim.x + threadIdx.x;
  if (i < n) p[i] = 0x007FFFFFu;  // fenc(-inf)
}

__global__ __launch_bounds__(THREADS) void bissect_pool(
    const float* __restrict__ hs, const float* __restrict__ mask,
    unsigned* __restrict__ pooled) {
  const int tid = threadIdx.x;
  const int b = blockIdx.x / CHUNKS;
  const int chunk = blockIdx.x % CHUNKS;
  const int wave = tid >> 6;
  const int lane = tid & 63;
  __shared__ float red[THREADS / 64][NL];

  const size_t layer_stride = (size_t)B_ * T_ * H_;

  float4 pmax = make_float4(-INFINITY, -INFINITY, -INFINITY, -INFINITY);

  for (int i = 0; i < TOK_PER_BLK; ++i) {
    const int t = chunk * TOK_PER_BLK + i;
    // layer 1 base for this token, this thread's float4 of H
    const float* base = hs + layer_stride + ((size_t)b * T_ + (size_t)t) * H_ + 4 * tid;

    float4 d[NL];
#pragma unroll
    for (int n = 0; n < NL; ++n)
      d[n] = *reinterpret_cast<const float4*>(base + (size_t)n * layer_stride);

    // v = mean over layers
    float4 v = d[0];
#pragma unroll
    for (int n = 1; n < NL; ++n) {
      v.x += d[n].x; v.y += d[n].y; v.z += d[n].z; v.w += d[n].w;
    }
    const float inv12 = 1.0f / 12.0f;
    v.x *= inv12; v.y *= inv12; v.z *= inv12; v.w *= inv12;

    // per-thread partial scores
    float s[NL];
#pragma unroll
    for (int n = 0; n < NL; ++n)
      s[n] = v.x * d[n].x + v.y * d[n].y + v.z * d[n].z + v.w * d[n].w;

    // 64-lane tree reduce (wave = 64 on gfx950)
#pragma unroll
    for (int off = 32; off >= 1; off >>= 1) {
#pragma unroll
      for (int n = 0; n < NL; ++n) s[n] += __shfl_xor(s[n], off);
    }

    // cross-wave reduce via LDS (static indexing only; rule #20)
    if (lane == 0) {
#pragma unroll
      for (int n = 0; n < NL; ++n) red[wave][n] = s[n];
    }
    __syncthreads();
#pragma unroll
    for (int n = 0; n < NL; ++n) s[n] = red[0][n] + red[1][n] + red[2][n];
    __syncthreads();  // protect red before next iteration's writes

    // softmax over the 12 layer scores (stable)
    float m = s[0];
#pragma unroll
    for (int n = 1; n < NL; ++n) m = fmaxf(m, s[n]);
    float e[NL], esum = 0.f;
#pragma unroll
    for (int n = 0; n < NL; ++n) { e[n] = __expf(s[n] - m); esum += e[n]; }
    const float scale = mask[b * T_ + t] / esum;

    // final = (sum_n d[n]*e[n]) * scale ; running max over tokens
    float4 fin = make_float4(0.f, 0.f, 0.f, 0.f);
#pragma unroll
    for (int n = 0; n < NL; ++n) {
      fin.x += d[n].x * e[n];
      fin.y += d[n].y * e[n];
      fin.z += d[n].z * e[n];
      fin.w += d[n].w * e[n];
    }
    pmax.x = fmaxf(pmax.x, fin.x * scale);
    pmax.y = fmaxf(pmax.y, fin.y * scale);
    pmax.z = fmaxf(pmax.z, fin.z * scale);
    pmax.w = fmaxf(pmax.w, fin.w * scale);
  }

  unsigned* p = pooled + (size_t)b * H_ + 4 * tid;
  atomicMax(p + 0, fenc(pmax.x));
  atomicMax(p + 1, fenc(pmax.y));
  atomicMax(p + 2, fenc(pmax.z));
  atomicMax(p + 3, fenc(pmax.w));
}

__global__ __launch_bounds__(256) void logits_kernel(
    const unsigned* __restrict__ pooled, const float* __restrict__ W,
    const float* __restrict__ bias, float* __restrict__ out) {
  const int b = blockIdx.x;
  const int tid = threadIdx.x;
  float a0 = 0.f, a1 = 0.f;
  for (int h = tid; h < H_; h += 256) {
    const float p = fdec(pooled[(size_t)b * H_ + h]);
    a0 += p * W[h];
    a1 += p * W[H_ + h];
  }
#pragma unroll
  for (int off = 32; off >= 1; off >>= 1) {
    a0 += __shfl_xor(a0, off);
    a1 += __shfl_xor(a1, off);
  }
  __shared__ float r0[4], r1[4];
  const int wave = tid >> 6, lane = tid & 63;
  if (lane == 0) { r0[wave] = a0; r1[wave] = a1; }
  __syncthreads();
  if (tid == 0) {
    out[b * 2 + 0] = r0[0] + r0[1] + r0[2] + r0[3] + bias[0];
    out[b * 2 + 1] = r1[0] + r1[1] + r1[2] + r1[3] + bias[1];
  }
}

extern "C" void kernel_launch(void* const* d_in, const int* in_sizes, int n_in,
                              void* d_out, int out_size, void* d_ws, size_t ws_size,
                              hipStream_t stream) {
  const float* hs   = (const float*)d_in[0];
  const float* mask = (const float*)d_in[1];
  const float* W    = (const float*)d_in[2];
  const float* bias = (const float*)d_in[3];
  float* out = (float*)d_out;
  unsigned* pooled = (unsigned*)d_ws;  // B_*H_ u32 = 96 KiB

  const int npool = B_ * H_;
  hipLaunchKernelGGL(init_pooled, dim3((npool + 255) / 256), dim3(256), 0, stream,
                     pooled, npool);
  hipLaunchKernelGGL(bissect_pool, dim3(B_ * CHUNKS), dim3(THREADS), 0, stream,
                     hs, mask, pooled);
  hipLaunchKernelGGL(logits_kernel, dim3(B_), dim3(256), 0, stream,
                     pooled, W, bias, out);
}